// Round 1
// baseline (1029.128 us; speedup 1.0000x reference)
//
#include <hip/hip_runtime.h>
#include <hip/hip_bf16.h>

#define NN 200000
#define EE 600000
#define DD 128

__device__ __forceinline__ float silu_f(float v) {
    return v * (1.0f / (1.0f + __expf(-v)));
}

// ---------------- degree (with self-loop) ----------------
__global__ void k_deg_init(float* __restrict__ deg) {
    int i = blockIdx.x * 256 + threadIdx.x;
    if (i < NN) deg[i] = 1.0f;  // self-loop contributes 1
}

__global__ void k_deg_count(const int* __restrict__ ei, float* __restrict__ deg) {
    int e = blockIdx.x * 256 + threadIdx.x;
    if (e < EE) unsafeAtomicAdd(&deg[ei[EE + e]], 1.0f);  // dst row
}

// ---------------- fused LN1 + GEMM (h = LN(x) @ W), epilogue: H bf16 + acc=h/deg ----------------
// block tile: 128 rows x 128 cols, 256 threads, 8x8 per-thread register tile.
__global__ __launch_bounds__(256) void k_ln1_gemm(
    const float* __restrict__ X, const float* __restrict__ W,
    const float* __restrict__ g, const float* __restrict__ b,
    const float* __restrict__ deg,
    __hip_bfloat16* __restrict__ H, float* __restrict__ acc0)
{
    __shared__ float As[16][128];   // A chunk, transposed: As[k][row]
    __shared__ float Bs[16][128];   // W chunk: Bs[k][col]
    __shared__ float mu_s[128], rs_s[128], gs[128], bsh[128];

    const int tid = threadIdx.x;
    const int row0 = blockIdx.x * 128;
    if (tid < 128) { gs[tid] = g[tid]; bsh[tid] = b[tid]; }

    // phase A: LN stats, one wave per row
    const int wv = tid >> 6, lane = tid & 63;
    for (int rr = 0; rr < 32; ++rr) {
        const int r = wv * 32 + rr;
        const int grow = row0 + r;
        float2 v = make_float2(0.f, 0.f);
        if (grow < NN) v = *(const float2*)&X[(size_t)grow * DD + lane * 2];
        float s = v.x + v.y;
        float s2 = v.x * v.x + v.y * v.y;
        for (int o = 32; o; o >>= 1) { s += __shfl_xor(s, o); s2 += __shfl_xor(s2, o); }
        if (lane == 0) {
            float mu = s * (1.f / DD);
            float var = s2 * (1.f / DD) - mu * mu;
            mu_s[r] = mu;
            rs_s[r] = rsqrtf(var + 1e-5f);
        }
    }
    __syncthreads();

    float acc[8][8];
#pragma unroll
    for (int i = 0; i < 8; ++i)
#pragma unroll
        for (int j = 0; j < 8; ++j) acc[i][j] = 0.f;

    const int tx = tid & 15, ty = tid >> 4;
    const int lr = tid >> 1, kq = tid & 1;  // A-chunk loader mapping
    const int growA = row0 + lr;
    const float muA = mu_s[lr], rsA = rs_s[lr];

    for (int k0 = 0; k0 < DD; k0 += 16) {
        {   // W chunk -> Bs (coalesced float4)
            const int f = tid * 8;
            const int kr = f >> 7, c = f & 127;
            *(float4*)&Bs[kr][c]     = *(const float4*)&W[(size_t)(k0 + kr) * DD + c];
            *(float4*)&Bs[kr][c + 4] = *(const float4*)&W[(size_t)(k0 + kr) * DD + c + 4];
        }
        {   // x chunk, LN-normalized, stored transposed
            float4 v0 = make_float4(0, 0, 0, 0), v1 = v0;
            if (growA < NN) {
                v0 = *(const float4*)&X[(size_t)growA * DD + k0 + kq * 8];
                v1 = *(const float4*)&X[(size_t)growA * DD + k0 + kq * 8 + 4];
            }
            const int kb = kq * 8;
            const int kg = k0 + kb;
            As[kb + 0][lr] = (v0.x - muA) * rsA * gs[kg + 0] + bsh[kg + 0];
            As[kb + 1][lr] = (v0.y - muA) * rsA * gs[kg + 1] + bsh[kg + 1];
            As[kb + 2][lr] = (v0.z - muA) * rsA * gs[kg + 2] + bsh[kg + 2];
            As[kb + 3][lr] = (v0.w - muA) * rsA * gs[kg + 3] + bsh[kg + 3];
            As[kb + 4][lr] = (v1.x - muA) * rsA * gs[kg + 4] + bsh[kg + 4];
            As[kb + 5][lr] = (v1.y - muA) * rsA * gs[kg + 5] + bsh[kg + 5];
            As[kb + 6][lr] = (v1.z - muA) * rsA * gs[kg + 6] + bsh[kg + 6];
            As[kb + 7][lr] = (v1.w - muA) * rsA * gs[kg + 7] + bsh[kg + 7];
        }
        __syncthreads();
#pragma unroll
        for (int kk = 0; kk < 16; ++kk) {
            float2 a0 = *(const float2*)&As[kk][ty * 2];
            float2 a1 = *(const float2*)&As[kk][ty * 2 + 32];
            float2 a2 = *(const float2*)&As[kk][ty * 2 + 64];
            float2 a3 = *(const float2*)&As[kk][ty * 2 + 96];
            float2 b0 = *(const float2*)&Bs[kk][tx * 2];
            float2 b1 = *(const float2*)&Bs[kk][tx * 2 + 32];
            float2 b2 = *(const float2*)&Bs[kk][tx * 2 + 64];
            float2 b3 = *(const float2*)&Bs[kk][tx * 2 + 96];
            float av[8] = {a0.x, a0.y, a1.x, a1.y, a2.x, a2.y, a3.x, a3.y};
            float bv[8] = {b0.x, b0.y, b1.x, b1.y, b2.x, b2.y, b3.x, b3.y};
#pragma unroll
            for (int i = 0; i < 8; ++i)
#pragma unroll
                for (int j = 0; j < 8; ++j) acc[i][j] += av[i] * bv[j];
        }
        __syncthreads();
    }

    // epilogue: H (bf16) and acc0 = h/deg (self-loop message, fp32)
#pragma unroll
    for (int i = 0; i < 8; ++i) {
        const int r = ty * 2 + (i & 1) + (i >> 1) * 32;
        const int grow = row0 + r;
        if (grow < NN) {
            const float w = 1.0f / deg[grow];
#pragma unroll
            for (int p = 0; p < 4; ++p) {
                const int c = tx * 2 + p * 32;
                const float hx = acc[i][p * 2], hy = acc[i][p * 2 + 1];
                __hip_bfloat162 hb;
                hb.x = __float2bfloat16(hx);
                hb.y = __float2bfloat16(hy);
                *(__hip_bfloat162*)&H[(size_t)grow * DD + c] = hb;
                *(float2*)&acc0[(size_t)grow * DD + c] = make_float2(hx * w, hy * w);
            }
        }
    }
}

// ---------------- edge scatter: acc[dst] += h[src] * norm ----------------
__global__ __launch_bounds__(256) void k_scatter(
    const int* __restrict__ ei, const __hip_bfloat16* __restrict__ H,
    const float* __restrict__ deg, float* __restrict__ acc0)
{
    const int e = blockIdx.x * 4 + (threadIdx.x >> 6);  // one wave per edge
    const int lane = threadIdx.x & 63;
    if (e >= EE) return;
    const int s = ei[e], d = ei[EE + e];
    const float nrm = rsqrtf(deg[s]) * rsqrtf(deg[d]);
    const __hip_bfloat162 hv = *(const __hip_bfloat162*)&H[(size_t)s * DD + lane * 2];
    unsafeAtomicAdd(&acc0[(size_t)d * DD + lane * 2 + 0], __bfloat162float(hv.x) * nrm);
    unsafeAtomicAdd(&acc0[(size_t)d * DD + lane * 2 + 1], __bfloat162float(hv.y) * nrm);
}

// ---------------- fused: x1 = x + a1*silu(acc+gcn_b); LN2; f=silu(x1n@FW+fb); out = x1 + a2*f ----------------
__global__ __launch_bounds__(256) void k_ln2_gemm_out(
    const float* __restrict__ X, const float* __restrict__ acc0,
    const float* __restrict__ gcnb,
    const float* __restrict__ a1p, const float* __restrict__ a2p,
    const float* __restrict__ g2, const float* __restrict__ b2,
    const float* __restrict__ FW, const float* __restrict__ fb,
    float* __restrict__ out)   // holds x1 during the kernel, then final output
{
    __shared__ float As[16][128];
    __shared__ float Bs[16][128];
    __shared__ float mu_s[128], rs_s[128], gs[128], bsh[128], fbs[128];

    const int tid = threadIdx.x;
    const int row0 = blockIdx.x * 128;
    if (tid < 128) { gs[tid] = g2[tid]; bsh[tid] = b2[tid]; fbs[tid] = fb[tid]; }

    const float a1 = *a1p;
    const int wv = tid >> 6, lane = tid & 63;
    const float2 gb = *(const float2*)&gcnb[lane * 2];

    // phase A: x1 = x + a1*silu(acc + gcn_b)  -> out (as scratch), plus LN2 stats
    for (int rr = 0; rr < 32; ++rr) {
        const int r = wv * 32 + rr;
        const int grow = row0 + r;
        float2 v = make_float2(0.f, 0.f);
        if (grow < NN) {
            const float2 xv = *(const float2*)&X[(size_t)grow * DD + lane * 2];
            const float2 av = *(const float2*)&acc0[(size_t)grow * DD + lane * 2];
            v.x = xv.x + a1 * silu_f(av.x + gb.x);
            v.y = xv.y + a1 * silu_f(av.y + gb.y);
            *(float2*)&out[(size_t)grow * DD + lane * 2] = v;
        }
        float s = v.x + v.y;
        float s2 = v.x * v.x + v.y * v.y;
        for (int o = 32; o; o >>= 1) { s += __shfl_xor(s, o); s2 += __shfl_xor(s2, o); }
        if (lane == 0) {
            float mu = s * (1.f / DD);
            float var = s2 * (1.f / DD) - mu * mu;
            mu_s[r] = mu;
            rs_s[r] = rsqrtf(var + 1e-5f);
        }
    }
    __syncthreads();

    float acc[8][8];
#pragma unroll
    for (int i = 0; i < 8; ++i)
#pragma unroll
        for (int j = 0; j < 8; ++j) acc[i][j] = 0.f;

    const int tx = tid & 15, ty = tid >> 4;
    const int lr = tid >> 1, kq = tid & 1;
    const int growA = row0 + lr;
    const float muA = mu_s[lr], rsA = rs_s[lr];

    for (int k0 = 0; k0 < DD; k0 += 16) {
        {
            const int f = tid * 8;
            const int kr = f >> 7, c = f & 127;
            *(float4*)&Bs[kr][c]     = *(const float4*)&FW[(size_t)(k0 + kr) * DD + c];
            *(float4*)&Bs[kr][c + 4] = *(const float4*)&FW[(size_t)(k0 + kr) * DD + c + 4];
        }
        {
            float4 v0 = make_float4(0, 0, 0, 0), v1 = v0;
            if (growA < NN) {
                v0 = *(const float4*)&out[(size_t)growA * DD + k0 + kq * 8];
                v1 = *(const float4*)&out[(size_t)growA * DD + k0 + kq * 8 + 4];
            }
            const int kb = kq * 8;
            const int kg = k0 + kb;
            As[kb + 0][lr] = (v0.x - muA) * rsA * gs[kg + 0] + bsh[kg + 0];
            As[kb + 1][lr] = (v0.y - muA) * rsA * gs[kg + 1] + bsh[kg + 1];
            As[kb + 2][lr] = (v0.z - muA) * rsA * gs[kg + 2] + bsh[kg + 2];
            As[kb + 3][lr] = (v0.w - muA) * rsA * gs[kg + 3] + bsh[kg + 3];
            As[kb + 4][lr] = (v1.x - muA) * rsA * gs[kg + 4] + bsh[kg + 4];
            As[kb + 5][lr] = (v1.y - muA) * rsA * gs[kg + 5] + bsh[kg + 5];
            As[kb + 6][lr] = (v1.z - muA) * rsA * gs[kg + 6] + bsh[kg + 6];
            As[kb + 7][lr] = (v1.w - muA) * rsA * gs[kg + 7] + bsh[kg + 7];
        }
        __syncthreads();
#pragma unroll
        for (int kk = 0; kk < 16; ++kk) {
            float2 a0 = *(const float2*)&As[kk][ty * 2];
            float2 a1v = *(const float2*)&As[kk][ty * 2 + 32];
            float2 a2v = *(const float2*)&As[kk][ty * 2 + 64];
            float2 a3 = *(const float2*)&As[kk][ty * 2 + 96];
            float2 b0 = *(const float2*)&Bs[kk][tx * 2];
            float2 b1 = *(const float2*)&Bs[kk][tx * 2 + 32];
            float2 b2v = *(const float2*)&Bs[kk][tx * 2 + 64];
            float2 b3 = *(const float2*)&Bs[kk][tx * 2 + 96];
            float av[8] = {a0.x, a0.y, a1v.x, a1v.y, a2v.x, a2v.y, a3.x, a3.y};
            float bv[8] = {b0.x, b0.y, b1.x, b1.y, b2v.x, b2v.y, b3.x, b3.y};
#pragma unroll
            for (int i = 0; i < 8; ++i)
#pragma unroll
                for (int j = 0; j < 8; ++j) acc[i][j] += av[i] * bv[j];
        }
        __syncthreads();
    }

    const float a2s = *a2p;
#pragma unroll
    for (int i = 0; i < 8; ++i) {
        const int r = ty * 2 + (i & 1) + (i >> 1) * 32;
        const int grow = row0 + r;
        if (grow < NN) {
#pragma unroll
            for (int p = 0; p < 4; ++p) {
                const int c = tx * 2 + p * 32;
                const float2 x1v = *(const float2*)&out[(size_t)grow * DD + c];
                float2 o;
                o.x = x1v.x + a2s * silu_f(acc[i][p * 2]     + fbs[c]);
                o.y = x1v.y + a2s * silu_f(acc[i][p * 2 + 1] + fbs[c + 1]);
                *(float2*)&out[(size_t)grow * DD + c] = o;
            }
        }
    }
}

extern "C" void kernel_launch(void* const* d_in, const int* in_sizes, int n_in,
                              void* d_out, int out_size, void* d_ws, size_t ws_size,
                              hipStream_t stream)
{
    const float* X  = (const float*)d_in[0];
    const int*   EI = (const int*)d_in[1];
    const float* g1 = (const float*)d_in[2];
    const float* b1 = (const float*)d_in[3];
    const float* GW = (const float*)d_in[4];
    const float* gb = (const float*)d_in[5];
    const float* a1 = (const float*)d_in[6];
    const float* a2 = (const float*)d_in[7];
    const float* g2 = (const float*)d_in[8];
    const float* b2 = (const float*)d_in[9];
    const float* FW = (const float*)d_in[10];
    const float* fb = (const float*)d_in[11];
    float* out = (float*)d_out;

    char* ws = (char*)d_ws;
    float*          deg  = (float*)ws;                           // 800,000 B
    __hip_bfloat16* H    = (__hip_bfloat16*)(ws + 800000);       // 51,200,000 B
    float*          acc0 = (float*)(ws + 800000 + 51200000);     // 102,400,000 B
    // total ws use: 154,400,000 B

    k_deg_init <<<(NN + 255) / 256, 256, 0, stream>>>(deg);
    k_deg_count<<<(EE + 255) / 256, 256, 0, stream>>>(EI, deg);
    k_ln1_gemm <<<(NN + 127) / 128, 256, 0, stream>>>(X, GW, g1, b1, deg, H, acc0);
    k_scatter  <<<(EE + 3) / 4, 256, 0, stream>>>(EI, H, deg, acc0);
    k_ln2_gemm_out<<<(NN + 127) / 128, 256, 0, stream>>>(X, acc0, gb, a1, a2, g2, b2, FW, fb, out);
}

// Round 2
// 576.027 us; speedup vs baseline: 1.7866x; 1.7866x over previous
//
#include <hip/hip_runtime.h>
#include <hip/hip_bf16.h>

#define NN 200000
#define EE 600000
#define DD 128
#define NB 782          // (NN + 255) / 256

__device__ __forceinline__ float silu_f(float v) {
    return v * (1.0f / (1.0f + __expf(-v)));
}

// ---------------- init: degi = 0 ----------------
__global__ void k_init(int* __restrict__ degi) {
    int i = blockIdx.x * 256 + threadIdx.x;
    if (i < NN) degi[i] = 0;
}

// ---------------- degree count (int atomics, excl self-loop) ----------------
__global__ void k_deg_count(const int* __restrict__ ei, int* __restrict__ degi) {
    int e = blockIdx.x * 256 + threadIdx.x;
    if (e < EE) atomicAdd(&degi[ei[EE + e]], 1);  // dst row
}

// ---------------- scan step 1: per-block exclusive scan + block totals ----------------
__global__ __launch_bounds__(256) void k_scan1(const int* __restrict__ degi,
                                               int* __restrict__ rs, int* __restrict__ bsum) {
    const int tid = threadIdx.x;
    const int i = blockIdx.x * 256 + tid;
    const int lane = tid & 63, wv = tid >> 6;
    int v = (i < NN) ? degi[i] : 0;
    int x = v;
#pragma unroll
    for (int o = 1; o < 64; o <<= 1) { int y = __shfl_up(x, o); if (lane >= o) x += y; }
    __shared__ int wsum[4];
    if (lane == 63) wsum[wv] = x;
    __syncthreads();
    int off = 0;
    for (int w = 0; w < wv; ++w) off += wsum[w];
    const int incl = x + off;
    if (i < NN) rs[i] = incl - v;           // exclusive within block
    if (tid == 255) bsum[blockIdx.x] = incl; // block total
}

// ---------------- scan step 2: scan the block totals (single wave) ----------------
__global__ void k_scan2(int* __restrict__ bsum) {
    const int lane = threadIdx.x;  // 64 threads
    int carry = 0;
    for (int base = 0; base < NB; base += 64) {
        const int i = base + lane;
        int v = (i < NB) ? bsum[i] : 0;
        int x = v;
#pragma unroll
        for (int o = 1; o < 64; o <<= 1) { int y = __shfl_up(x, o); if (lane >= o) x += y; }
        if (i < NB) bsum[i] = x - v + carry;
        carry += __shfl(x, 63);
    }
}

// ---------------- scan step 3: add block offsets, init cursor ----------------
__global__ void k_scan3(int* __restrict__ rs, const int* __restrict__ bsum,
                        int* __restrict__ cursor) {
    const int i = blockIdx.x * 256 + threadIdx.x;
    if (i < NN) {
        const int v = rs[i] + bsum[blockIdx.x];
        rs[i] = v;
        cursor[i] = v;
    }
}

// ---------------- CSR fill ----------------
__global__ void k_fill(const int* __restrict__ ei, int* __restrict__ cursor,
                       int* __restrict__ srcs) {
    const int e = blockIdx.x * 256 + threadIdx.x;
    if (e < EE) {
        const int s = ei[e], d = ei[EE + e];
        const int pos = atomicAdd(&cursor[d], 1);
        srcs[pos] = s;
    }
}

// ---------------- fused LN1 + GEMM (h = LN(x) @ W) -> H bf16 ----------------
// block tile: 128 rows x 128 cols, 256 threads, 8x8 per-thread register tile.
__global__ __launch_bounds__(256) void k_ln1_gemm(
    const float* __restrict__ X, const float* __restrict__ W,
    const float* __restrict__ g, const float* __restrict__ b,
    __hip_bfloat16* __restrict__ H)
{
    __shared__ float As[16][128];   // A chunk, transposed: As[k][row]
    __shared__ float Bs[16][128];   // W chunk: Bs[k][col]
    __shared__ float mu_s[128], rs_s[128], gs[128], bsh[128];

    const int tid = threadIdx.x;
    const int row0 = blockIdx.x * 128;
    if (tid < 128) { gs[tid] = g[tid]; bsh[tid] = b[tid]; }

    // phase A: LN stats, one wave per row
    const int wv = tid >> 6, lane = tid & 63;
    for (int rr = 0; rr < 32; ++rr) {
        const int r = wv * 32 + rr;
        const int grow = row0 + r;
        float2 v = make_float2(0.f, 0.f);
        if (grow < NN) v = *(const float2*)&X[(size_t)grow * DD + lane * 2];
        float s = v.x + v.y;
        float s2 = v.x * v.x + v.y * v.y;
        for (int o = 32; o; o >>= 1) { s += __shfl_xor(s, o); s2 += __shfl_xor(s2, o); }
        if (lane == 0) {
            float mu = s * (1.f / DD);
            float var = s2 * (1.f / DD) - mu * mu;
            mu_s[r] = mu;
            rs_s[r] = rsqrtf(var + 1e-5f);
        }
    }
    __syncthreads();

    float acc[8][8];
#pragma unroll
    for (int i = 0; i < 8; ++i)
#pragma unroll
        for (int j = 0; j < 8; ++j) acc[i][j] = 0.f;

    const int tx = tid & 15, ty = tid >> 4;
    const int lr = tid >> 1, kq = tid & 1;  // A-chunk loader mapping
    const int growA = row0 + lr;
    const float muA = mu_s[lr], rsA = rs_s[lr];

    for (int k0 = 0; k0 < DD; k0 += 16) {
        {   // W chunk -> Bs (coalesced float4)
            const int f = tid * 8;
            const int kr = f >> 7, c = f & 127;
            *(float4*)&Bs[kr][c]     = *(const float4*)&W[(size_t)(k0 + kr) * DD + c];
            *(float4*)&Bs[kr][c + 4] = *(const float4*)&W[(size_t)(k0 + kr) * DD + c + 4];
        }
        {   // x chunk, LN-normalized, stored transposed
            float4 v0 = make_float4(0, 0, 0, 0), v1 = v0;
            if (growA < NN) {
                v0 = *(const float4*)&X[(size_t)growA * DD + k0 + kq * 8];
                v1 = *(const float4*)&X[(size_t)growA * DD + k0 + kq * 8 + 4];
            }
            const int kb = kq * 8;
            const int kg = k0 + kb;
            As[kb + 0][lr] = (v0.x - muA) * rsA * gs[kg + 0] + bsh[kg + 0];
            As[kb + 1][lr] = (v0.y - muA) * rsA * gs[kg + 1] + bsh[kg + 1];
            As[kb + 2][lr] = (v0.z - muA) * rsA * gs[kg + 2] + bsh[kg + 2];
            As[kb + 3][lr] = (v0.w - muA) * rsA * gs[kg + 3] + bsh[kg + 3];
            As[kb + 4][lr] = (v1.x - muA) * rsA * gs[kg + 4] + bsh[kg + 4];
            As[kb + 5][lr] = (v1.y - muA) * rsA * gs[kg + 5] + bsh[kg + 5];
            As[kb + 6][lr] = (v1.z - muA) * rsA * gs[kg + 6] + bsh[kg + 6];
            As[kb + 7][lr] = (v1.w - muA) * rsA * gs[kg + 7] + bsh[kg + 7];
        }
        __syncthreads();
#pragma unroll
        for (int kk = 0; kk < 16; ++kk) {
            float2 a0 = *(const float2*)&As[kk][ty * 2];
            float2 a1 = *(const float2*)&As[kk][ty * 2 + 32];
            float2 a2 = *(const float2*)&As[kk][ty * 2 + 64];
            float2 a3 = *(const float2*)&As[kk][ty * 2 + 96];
            float2 b0 = *(const float2*)&Bs[kk][tx * 2];
            float2 b1 = *(const float2*)&Bs[kk][tx * 2 + 32];
            float2 b2 = *(const float2*)&Bs[kk][tx * 2 + 64];
            float2 b3 = *(const float2*)&Bs[kk][tx * 2 + 96];
            float av[8] = {a0.x, a0.y, a1.x, a1.y, a2.x, a2.y, a3.x, a3.y};
            float bv[8] = {b0.x, b0.y, b1.x, b1.y, b2.x, b2.y, b3.x, b3.y};
#pragma unroll
            for (int i = 0; i < 8; ++i)
#pragma unroll
                for (int j = 0; j < 8; ++j) acc[i][j] += av[i] * bv[j];
        }
        __syncthreads();
    }

    // epilogue: H bf16
#pragma unroll
    for (int i = 0; i < 8; ++i) {
        const int r = ty * 2 + (i & 1) + (i >> 1) * 32;
        const int grow = row0 + r;
        if (grow < NN) {
#pragma unroll
            for (int p = 0; p < 4; ++p) {
                const int c = tx * 2 + p * 32;
                __hip_bfloat162 hb;
                hb.x = __float2bfloat16(acc[i][p * 2]);
                hb.y = __float2bfloat16(acc[i][p * 2 + 1]);
                *(__hip_bfloat162*)&H[(size_t)grow * DD + c] = hb;
            }
        }
    }
}

// ---------------- gather: per-node wave; fused x1 = x + a1*silu(gcn) + LN2 stats ----------------
__global__ __launch_bounds__(256) void k_gather(
    const int* __restrict__ degi, const int* __restrict__ rs, const int* __restrict__ srcs,
    const unsigned int* __restrict__ Hu,       // H as bf16x2 dwords
    const float* __restrict__ X, const float* __restrict__ gcnb,
    const float* __restrict__ a1p,
    float* __restrict__ out,                   // x1
    float* __restrict__ mu_arr, float* __restrict__ rs_arr)
{
    const int node = blockIdx.x * 4 + (threadIdx.x >> 6);
    const int lane = threadIdx.x & 63;
    if (node >= NN) return;

    const int dcount = degi[node];
    const float degd = 1.0f + (float)dcount;
    const float dinv_d = rsqrtf(degd);

    // self-loop message: h[node] / deg[node]
    unsigned int u = Hu[(size_t)node * 64 + lane];
    float2 acc;
    acc.x = __uint_as_float(u << 16) / degd;
    acc.y = __uint_as_float(u & 0xffff0000u) / degd;

    int base = rs[node];
    int remaining = dcount;
    while (remaining > 0) {
        const int cnt = remaining < 64 ? remaining : 64;
        int sp = 0;
        if (lane < cnt) sp = srcs[base + lane];
        int dg = 0;
        if (lane < cnt) dg = degi[sp];
        const float nr = rsqrtf(1.0f + (float)dg) * dinv_d;
        for (int t = 0; t < cnt; ++t) {
            const int s = __shfl(sp, t);
            const float nrm = __shfl(nr, t);
            const unsigned int hu = Hu[(size_t)s * 64 + lane];
            acc.x += __uint_as_float(hu << 16) * nrm;
            acc.y += __uint_as_float(hu & 0xffff0000u) * nrm;
        }
        remaining -= cnt;
        base += cnt;
    }

    const float a1 = *a1p;
    const float2 gb = ((const float2*)gcnb)[lane];
    const float2 xv = ((const float2*)X)[(size_t)node * 64 + lane];
    float2 o;
    o.x = xv.x + a1 * silu_f(acc.x + gb.x);
    o.y = xv.y + a1 * silu_f(acc.y + gb.y);
    ((float2*)out)[(size_t)node * 64 + lane] = o;

    // LN2 stats for this row
    float s = o.x + o.y;
    float s2 = o.x * o.x + o.y * o.y;
    for (int of = 32; of; of >>= 1) { s += __shfl_xor(s, of); s2 += __shfl_xor(s2, of); }
    if (lane == 0) {
        const float mu = s * (1.f / DD);
        const float var = s2 * (1.f / DD) - mu * mu;
        mu_arr[node] = mu;
        rs_arr[node] = rsqrtf(var + 1e-5f);
    }
}

// ---------------- fused: LN2(x1) @ FW ; out = x1 + a2*silu(f + fb) ----------------
__global__ __launch_bounds__(256) void k_ln2_gemm_out(
    const float* __restrict__ a2p,
    const float* __restrict__ g2, const float* __restrict__ b2,
    const float* __restrict__ FW, const float* __restrict__ fb,
    const float* __restrict__ mu_arr, const float* __restrict__ rs_arr,
    float* __restrict__ out)   // holds x1 on entry, final output on exit
{
    __shared__ float As[16][128];
    __shared__ float Bs[16][128];
    __shared__ float mu_s[128], rs_s[128], gs[128], bsh[128], fbs[128];

    const int tid = threadIdx.x;
    const int row0 = blockIdx.x * 128;
    if (tid < 128) {
        gs[tid] = g2[tid]; bsh[tid] = b2[tid]; fbs[tid] = fb[tid];
        const int grow = row0 + tid;
        if (grow < NN) { mu_s[tid] = mu_arr[grow]; rs_s[tid] = rs_arr[grow]; }
        else           { mu_s[tid] = 0.f;          rs_s[tid] = 0.f; }
    }
    __syncthreads();

    float acc[8][8];
#pragma unroll
    for (int i = 0; i < 8; ++i)
#pragma unroll
        for (int j = 0; j < 8; ++j) acc[i][j] = 0.f;

    const int tx = tid & 15, ty = tid >> 4;
    const int lr = tid >> 1, kq = tid & 1;
    const int growA = row0 + lr;
    const float muA = mu_s[lr], rsA = rs_s[lr];

    for (int k0 = 0; k0 < DD; k0 += 16) {
        {
            const int f = tid * 8;
            const int kr = f >> 7, c = f & 127;
            *(float4*)&Bs[kr][c]     = *(const float4*)&FW[(size_t)(k0 + kr) * DD + c];
            *(float4*)&Bs[kr][c + 4] = *(const float4*)&FW[(size_t)(k0 + kr) * DD + c + 4];
        }
        {
            float4 v0 = make_float4(0, 0, 0, 0), v1 = v0;
            if (growA < NN) {
                v0 = *(const float4*)&out[(size_t)growA * DD + k0 + kq * 8];
                v1 = *(const float4*)&out[(size_t)growA * DD + k0 + kq * 8 + 4];
            }
            const int kb = kq * 8;
            const int kg = k0 + kb;
            As[kb + 0][lr] = (v0.x - muA) * rsA * gs[kg + 0] + bsh[kg + 0];
            As[kb + 1][lr] = (v0.y - muA) * rsA * gs[kg + 1] + bsh[kg + 1];
            As[kb + 2][lr] = (v0.z - muA) * rsA * gs[kg + 2] + bsh[kg + 2];
            As[kb + 3][lr] = (v0.w - muA) * rsA * gs[kg + 3] + bsh[kg + 3];
            As[kb + 4][lr] = (v1.x - muA) * rsA * gs[kg + 4] + bsh[kg + 4];
            As[kb + 5][lr] = (v1.y - muA) * rsA * gs[kg + 5] + bsh[kg + 5];
            As[kb + 6][lr] = (v1.z - muA) * rsA * gs[kg + 6] + bsh[kg + 6];
            As[kb + 7][lr] = (v1.w - muA) * rsA * gs[kg + 7] + bsh[kg + 7];
        }
        __syncthreads();
#pragma unroll
        for (int kk = 0; kk < 16; ++kk) {
            float2 a0 = *(const float2*)&As[kk][ty * 2];
            float2 a1v = *(const float2*)&As[kk][ty * 2 + 32];
            float2 a2v = *(const float2*)&As[kk][ty * 2 + 64];
            float2 a3 = *(const float2*)&As[kk][ty * 2 + 96];
            float2 b0 = *(const float2*)&Bs[kk][tx * 2];
            float2 b1 = *(const float2*)&Bs[kk][tx * 2 + 32];
            float2 b2v = *(const float2*)&Bs[kk][tx * 2 + 64];
            float2 b3 = *(const float2*)&Bs[kk][tx * 2 + 96];
            float av[8] = {a0.x, a0.y, a1v.x, a1v.y, a2v.x, a2v.y, a3.x, a3.y};
            float bv[8] = {b0.x, b0.y, b1.x, b1.y, b2v.x, b2v.y, b3.x, b3.y};
#pragma unroll
            for (int i = 0; i < 8; ++i)
#pragma unroll
                for (int j = 0; j < 8; ++j) acc[i][j] += av[i] * bv[j];
        }
        __syncthreads();
    }

    const float a2s = *a2p;
#pragma unroll
    for (int i = 0; i < 8; ++i) {
        const int r = ty * 2 + (i & 1) + (i >> 1) * 32;
        const int grow = row0 + r;
        if (grow < NN) {
#pragma unroll
            for (int p = 0; p < 4; ++p) {
                const int c = tx * 2 + p * 32;
                const float2 x1v = *(const float2*)&out[(size_t)grow * DD + c];
                float2 o;
                o.x = x1v.x + a2s * silu_f(acc[i][p * 2]     + fbs[c]);
                o.y = x1v.y + a2s * silu_f(acc[i][p * 2 + 1] + fbs[c + 1]);
                *(float2*)&out[(size_t)grow * DD + c] = o;
            }
        }
    }
}

extern "C" void kernel_launch(void* const* d_in, const int* in_sizes, int n_in,
                              void* d_out, int out_size, void* d_ws, size_t ws_size,
                              hipStream_t stream)
{
    const float* X  = (const float*)d_in[0];
    const int*   EI = (const int*)d_in[1];
    const float* g1 = (const float*)d_in[2];
    const float* b1 = (const float*)d_in[3];
    const float* GW = (const float*)d_in[4];
    const float* gb = (const float*)d_in[5];
    const float* a1 = (const float*)d_in[6];
    const float* a2 = (const float*)d_in[7];
    const float* g2 = (const float*)d_in[8];
    const float* b2 = (const float*)d_in[9];
    const float* FW = (const float*)d_in[10];
    const float* fb = (const float*)d_in[11];
    float* out = (float*)d_out;

    char* ws = (char*)d_ws;
    int*            degi    = (int*)ws;                        //    800,000 B
    __hip_bfloat16* H       = (__hip_bfloat16*)(ws + 800000);  // 51,200,000 B
    int*            rowst   = (int*)(ws + 52000000);           //    800,000 B
    int*            cursor  = (int*)(ws + 52800000);           //    800,000 B
    int*            srcs    = (int*)(ws + 53600000);           //  2,400,000 B
    int*            bsum    = (int*)(ws + 56000000);           //      3,200 B
    float*          mu_arr  = (float*)(ws + 56016000);         //    800,000 B
    float*          rs_arr  = (float*)(ws + 56816000);         //    800,000 B
    // total ws use: 57,616,000 B

    k_init     <<<NB, 256, 0, stream>>>(degi);
    k_deg_count<<<(EE + 255) / 256, 256, 0, stream>>>(EI, degi);
    k_ln1_gemm <<<(NN + 127) / 128, 256, 0, stream>>>(X, GW, g1, b1, H);
    k_scan1    <<<NB, 256, 0, stream>>>(degi, rowst, bsum);
    k_scan2    <<<1, 64, 0, stream>>>(bsum);
    k_scan3    <<<NB, 256, 0, stream>>>(rowst, bsum, cursor);
    k_fill     <<<(EE + 255) / 256, 256, 0, stream>>>(EI, cursor, srcs);
    k_gather   <<<(NN + 3) / 4, 256, 0, stream>>>(degi, rowst, srcs, (const unsigned int*)H,
                                                  X, gb, a1, out, mu_arr, rs_arr);
    k_ln2_gemm_out<<<(NN + 127) / 128, 256, 0, stream>>>(a2, g2, b2, FW, fb, mu_arr, rs_arr, out);
}

// Round 11
// 509.348 us; speedup vs baseline: 2.0205x; 1.1309x over previous
//
#include <hip/hip_runtime.h>
#include <hip/hip_bf16.h>

#define NN 200000
#define EE 600000
#define DD 128
#define NB 782          // (NN + 255) / 256

typedef __attribute__((ext_vector_type(8))) short short8v;   // 8 bf16 = 4 VGPRs
typedef __attribute__((ext_vector_type(4))) float f32x4;

__device__ __forceinline__ float silu_f(float v) {
    return v * (1.0f / (1.0f + __expf(-v)));
}

// ---------------- init: degi = 0 ----------------
__global__ void k_init(int* __restrict__ degi) {
    int i = blockIdx.x * 256 + threadIdx.x;
    if (i < NN) degi[i] = 0;
}

// ---------------- degree count (int atomics, excl self-loop) ----------------
__global__ void k_deg_count(const int* __restrict__ ei, int* __restrict__ degi) {
    int e = blockIdx.x * 256 + threadIdx.x;
    if (e < EE) atomicAdd(&degi[ei[EE + e]], 1);  // dst row
}

// ---------------- prep: W,FW (fp32 [k][col]) -> Wt,FWt (bf16 [col][k]) ----------------
__global__ void k_prep(const float* __restrict__ W, const float* __restrict__ FW,
                       unsigned short* __restrict__ Wt, unsigned short* __restrict__ FWt) {
    const int gid = blockIdx.x * 256 + threadIdx.x;  // [0, 8192)
    const int id = gid & 4095;
    const int col = id >> 5;
    const int kb = (id & 31) * 4;
    const float* src = (gid < 4096) ? W : FW;
    unsigned short* dst = (gid < 4096) ? Wt : FWt;
    unsigned short v[4];
#pragma unroll
    for (int i = 0; i < 4; ++i) {
        __hip_bfloat16 h = __float2bfloat16(src[(size_t)(kb + i) * DD + col]);
        v[i] = *(unsigned short*)&h;
    }
    *(uint2*)&dst[col * DD + kb] = *(uint2*)v;
}

// ---------------- scan step 1: per-block exclusive scan + block totals ----------------
__global__ __launch_bounds__(256) void k_scan1(const int* __restrict__ degi,
                                               int* __restrict__ rs, int* __restrict__ bsum) {
    const int tid = threadIdx.x;
    const int i = blockIdx.x * 256 + tid;
    const int lane = tid & 63, wv = tid >> 6;
    int v = (i < NN) ? degi[i] : 0;
    int x = v;
#pragma unroll
    for (int o = 1; o < 64; o <<= 1) { int y = __shfl_up(x, o); if (lane >= o) x += y; }
    __shared__ int wsum[4];
    if (lane == 63) wsum[wv] = x;
    __syncthreads();
    int off = 0;
    for (int w = 0; w < wv; ++w) off += wsum[w];
    const int incl = x + off;
    if (i < NN) rs[i] = incl - v;
    if (tid == 255) bsum[blockIdx.x] = incl;
}

// ---------------- scan step 2: scan the block totals (single wave) ----------------
__global__ void k_scan2(int* __restrict__ bsum) {
    const int lane = threadIdx.x;  // 64 threads
    int carry = 0;
    for (int base = 0; base < NB; base += 64) {
        const int i = base + lane;
        int v = (i < NB) ? bsum[i] : 0;
        int x = v;
#pragma unroll
        for (int o = 1; o < 64; o <<= 1) { int y = __shfl_up(x, o); if (lane >= o) x += y; }
        if (i < NB) bsum[i] = x - v + carry;
        carry += __shfl(x, 63);
    }
}

// ---------------- scan step 3: add block offsets, init cursor ----------------
__global__ void k_scan3(int* __restrict__ rs, const int* __restrict__ bsum,
                        int* __restrict__ cursor) {
    const int i = blockIdx.x * 256 + threadIdx.x;
    if (i < NN) {
        const int v = rs[i] + bsum[blockIdx.x];
        rs[i] = v;
        cursor[i] = v;
    }
}

// ---------------- CSR fill ----------------
__global__ void k_fill(const int* __restrict__ ei, int* __restrict__ cursor,
                       int* __restrict__ srcs) {
    const int e = blockIdx.x * 256 + threadIdx.x;
    if (e < EE) {
        const int s = ei[e], d = ei[EE + e];
        const int pos = atomicAdd(&cursor[d], 1);
        srcs[pos] = s;
    }
}

// ---------------- fused LN1 + bf16 MFMA GEMM: H = bf16( (LN(x)*g+b) @ W ) ----------------
// 256 thr = 4 waves; block tile 128 rows x 128 cols; wave -> 32-col strip.
__global__ __launch_bounds__(256) void k_ln1_gemm(
    const float* __restrict__ X, const unsigned short* __restrict__ Wt,
    const float* __restrict__ g, const float* __restrict__ b,
    unsigned short* __restrict__ H)
{
    __shared__ __align__(16) char As[128 * 256];   // 32 KB swizzled bf16 rows

    const int tid = threadIdx.x;
    const int w = tid >> 6, lane = tid & 63;
    const int lm = lane & 15, lg = lane >> 4;
    const int row0 = blockIdx.x * 128;

    // B fragments (W^T cols for this wave's strip) -> registers, L1-resident
    short8v bfrag[2][4];
#pragma unroll
    for (int ct = 0; ct < 2; ++ct)
#pragma unroll
        for (int ks = 0; ks < 4; ++ks) {
            const int col = w * 32 + ct * 16 + lm;
            bfrag[ct][ks] = *(const short8v*)((const char*)Wt + col * 256 + ks * 64 + lg * 16);
        }

    // phase A: LN stats (butterfly) + normalized bf16 -> As (XOR-swizzled)
    const float2 gv = *(const float2*)&g[lane * 2];
    const float2 bv = *(const float2*)&b[lane * 2];
    for (int rr = 0; rr < 32; ++rr) {
        const int r = w * 32 + rr;
        const int grow = row0 + r;
        float2 v = make_float2(0.f, 0.f);
        if (grow < NN) v = *(const float2*)&X[(size_t)grow * DD + lane * 2];
        float s = v.x + v.y, s2 = v.x * v.x + v.y * v.y;
#pragma unroll
        for (int o = 32; o; o >>= 1) { s += __shfl_xor(s, o); s2 += __shfl_xor(s2, o); }
        const float mu = s * (1.f / DD);
        const float rsv = rsqrtf(s2 * (1.f / DD) - mu * mu + 1e-5f);
        __hip_bfloat162 hb;
        hb.x = __float2bfloat16((v.x - mu) * rsv * gv.x + bv.x);
        hb.y = __float2bfloat16((v.y - mu) * rsv * gv.y + bv.y);
        *(unsigned int*)(As + r * 256 + ((lane * 4) ^ ((r & 7) << 4))) = *(unsigned int*)&hb;
    }
    __syncthreads();

    // phase B: MFMA
    f32x4 acc[8][2];
#pragma unroll
    for (int rt = 0; rt < 8; ++rt) {
        acc[rt][0] = (f32x4){0.f, 0.f, 0.f, 0.f};
        acc[rt][1] = (f32x4){0.f, 0.f, 0.f, 0.f};
    }
#pragma unroll
    for (int ks = 0; ks < 4; ++ks) {
#pragma unroll
        for (int rt = 0; rt < 8; ++rt) {
            const int row = rt * 16 + lm;
            const short8v a = *(const short8v*)(As + row * 256 + ((ks * 64 + lg * 16) ^ ((row & 7) << 4)));
            acc[rt][0] = __builtin_amdgcn_mfma_f32_16x16x32_bf16(a, bfrag[0][ks], acc[rt][0], 0, 0, 0);
            acc[rt][1] = __builtin_amdgcn_mfma_f32_16x16x32_bf16(a, bfrag[1][ks], acc[rt][1], 0, 0, 0);
        }
    }

    // epilogue: H bf16 (C/D layout: col = lane&15, row = (lane>>4)*4 + i)
#pragma unroll
    for (int rt = 0; rt < 8; ++rt)
#pragma unroll
        for (int ct = 0; ct < 2; ++ct)
#pragma unroll
            for (int i = 0; i < 4; ++i) {
                const int grow = row0 + rt * 16 + lg * 4 + i;
                if (grow < NN) {
                    const int col = w * 32 + ct * 16 + lm;
                    __hip_bfloat16 hv = __float2bfloat16(acc[rt][ct][i]);
                    H[(size_t)grow * DD + col] = *(unsigned short*)&hv;
                }
            }
}

// ---------------- gather: per-node wave; fused x1 = x + a1*silu(gcn) + LN2 stats ----------------
__global__ __launch_bounds__(256) void k_gather(
    const int* __restrict__ degi, const int* __restrict__ rs, const int* __restrict__ srcs,
    const unsigned int* __restrict__ Hu,       // H as bf16x2 dwords
    const float* __restrict__ X, const float* __restrict__ gcnb,
    const float* __restrict__ a1p,
    float* __restrict__ out,                   // x1
    float* __restrict__ mu_arr, float* __restrict__ rs_arr)
{
    const int node = blockIdx.x * 4 + (threadIdx.x >> 6);
    const int lane = threadIdx.x & 63;
    if (node >= NN) return;

    const int dcount = degi[node];
    const float degd = 1.0f + (float)dcount;
    const float dinv_d = rsqrtf(degd);

    unsigned int u = Hu[(size_t)node * 64 + lane];
    float2 acc;
    acc.x = __uint_as_float(u << 16) / degd;
    acc.y = __uint_as_float(u & 0xffff0000u) / degd;

    int base = rs[node];
    int remaining = dcount;
    while (remaining > 0) {
        const int cnt = remaining < 64 ? remaining : 64;
        int sp = 0;
        if (lane < cnt) sp = srcs[base + lane];
        int dg = 0;
        if (lane < cnt) dg = degi[sp];
        const float nr = rsqrtf(1.0f + (float)dg) * dinv_d;
        for (int t = 0; t < cnt; ++t) {
            const int s = __shfl(sp, t);
            const float nrm = __shfl(nr, t);
            const unsigned int hu = Hu[(size_t)s * 64 + lane];
            acc.x += __uint_as_float(hu << 16) * nrm;
            acc.y += __uint_as_float(hu & 0xffff0000u) * nrm;
        }
        remaining -= cnt;
        base += cnt;
    }

    const float a1 = *a1p;
    const float2 gb = ((const float2*)gcnb)[lane];
    const float2 xv = ((const float2*)X)[(size_t)node * 64 + lane];
    float2 o;
    o.x = xv.x + a1 * silu_f(acc.x + gb.x);
    o.y = xv.y + a1 * silu_f(acc.y + gb.y);
    ((float2*)out)[(size_t)node * 64 + lane] = o;

    float s = o.x + o.y;
    float s2 = o.x * o.x + o.y * o.y;
    for (int of = 32; of; of >>= 1) { s += __shfl_xor(s, of); s2 += __shfl_xor(s2, of); }
    if (lane == 0) {
        const float mu = s * (1.f / DD);
        const float var = s2 * (1.f / DD) - mu * mu;
        mu_arr[node] = mu;
        rs_arr[node] = rsqrtf(var + 1e-5f);
    }
}

// ---------------- fused LN2 + bf16 MFMA GEMM + epilogue: out = x1 + a2*silu(f + fb) ----------------
__global__ __launch_bounds__(256) void k_ln2_gemm(
    const unsigned short* __restrict__ FWt,
    const float* __restrict__ g2, const float* __restrict__ b2,
    const float* __restrict__ fb, const float* __restrict__ a2p,
    const float* __restrict__ mu_arr, const float* __restrict__ rs_arr,
    float* __restrict__ out)   // x1 on entry, final output on exit
{
    __shared__ __align__(16) char As[128 * 256];

    const int tid = threadIdx.x;
    const int w = tid >> 6, lane = tid & 63;
    const int lm = lane & 15, lg = lane >> 4;
    const int row0 = blockIdx.x * 128;

    short8v bfrag[2][4];
#pragma unroll
    for (int ct = 0; ct < 2; ++ct)
#pragma unroll
        for (int ks = 0; ks < 4; ++ks) {
            const int col = w * 32 + ct * 16 + lm;
            bfrag[ct][ks] = *(const short8v*)((const char*)FWt + col * 256 + ks * 64 + lg * 16);
        }
    const float fbv0 = fb[w * 32 + lm];
    const float fbv1 = fb[w * 32 + 16 + lm];

    // phase A: normalize x1 with precomputed stats -> As
    const float2 gv = *(const float2*)&g2[lane * 2];
    const float2 bv = *(const float2*)&b2[lane * 2];
    for (int rr = 0; rr < 32; ++rr) {
        const int r = w * 32 + rr;
        const int grow = row0 + r;
        float2 v = make_float2(0.f, 0.f);
        float mu = 0.f, rsv = 0.f;
        if (grow < NN) {
            v = *(const float2*)&out[(size_t)grow * DD + lane * 2];
            mu = mu_arr[grow];
            rsv = rs_arr[grow];
        }
        __hip_bfloat162 hb;
        hb.x = __float2bfloat16((v.x - mu) * rsv * gv.x + bv.x);
        hb.y = __float2bfloat16((v.y - mu) * rsv * gv.y + bv.y);
        *(unsigned int*)(As + r * 256 + ((lane * 4) ^ ((r & 7) << 4))) = *(unsigned int*)&hb;
    }
    __syncthreads();

    f32x4 acc[8][2];
#pragma unroll
    for (int rt = 0; rt < 8; ++rt) {
        acc[rt][0] = (f32x4){0.f, 0.f, 0.f, 0.f};
        acc[rt][1] = (f32x4){0.f, 0.f, 0.f, 0.f};
    }
#pragma unroll
    for (int ks = 0; ks < 4; ++ks) {
#pragma unroll
        for (int rt = 0; rt < 8; ++rt) {
            const int row = rt * 16 + lm;
            const short8v a = *(const short8v*)(As + row * 256 + ((ks * 64 + lg * 16) ^ ((row & 7) << 4)));
            acc[rt][0] = __builtin_amdgcn_mfma_f32_16x16x32_bf16(a, bfrag[0][ks], acc[rt][0], 0, 0, 0);
            acc[rt][1] = __builtin_amdgcn_mfma_f32_16x16x32_bf16(a, bfrag[1][ks], acc[rt][1], 0, 0, 0);
        }
    }

    const float a2 = *a2p;
#pragma unroll
    for (int rt = 0; rt < 8; ++rt)
#pragma unroll
        for (int ct = 0; ct < 2; ++ct)
#pragma unroll
            for (int i = 0; i < 4; ++i) {
                const int grow = row0 + rt * 16 + lg * 4 + i;
                if (grow < NN) {
                    const int col = w * 32 + ct * 16 + lm;
                    const float fbc = ct ? fbv1 : fbv0;
                    const size_t idx = (size_t)grow * DD + col;
                    out[idx] = out[idx] + a2 * silu_f(acc[rt][ct][i] + fbc);
                }
            }
}

extern "C" void kernel_launch(void* const* d_in, const int* in_sizes, int n_in,
                              void* d_out, int out_size, void* d_ws, size_t ws_size,
                              hipStream_t stream)
{
    const float* X  = (const float*)d_in[0];
    const int*   EI = (const int*)d_in[1];
    const float* g1 = (const float*)d_in[2];
    const float* b1 = (const float*)d_in[3];
    const float* GW = (const float*)d_in[4];
    const float* gb = (const float*)d_in[5];
    const float* a1 = (const float*)d_in[6];
    const float* a2 = (const float*)d_in[7];
    const float* g2 = (const float*)d_in[8];
    const float* b2 = (const float*)d_in[9];
    const float* FW = (const float*)d_in[10];
    const float* fb = (const float*)d_in[11];
    float* out = (float*)d_out;

    char* ws = (char*)d_ws;
    int*            degi    = (int*)ws;                        //    800,000 B
    unsigned short* H       = (unsigned short*)(ws + 800000);  // 51,200,000 B
    int*            rowst   = (int*)(ws + 52000000);           //    800,000 B
    int*            cursor  = (int*)(ws + 52800000);           //    800,000 B
    int*            srcs    = (int*)(ws + 53600000);           //  2,400,000 B
    int*            bsum    = (int*)(ws + 56000000);           //      3,200 B
    float*          mu_arr  = (float*)(ws + 56016000);         //    800,000 B
    float*          rs_arr  = (float*)(ws + 56816000);         //    800,000 B
    unsigned short* Wt      = (unsigned short*)(ws + 57616000);//     32,768 B
    unsigned short* FWt     = (unsigned short*)(ws + 57648768);//     32,768 B
    // total ws use: 57,681,536 B

    k_init     <<<NB, 256, 0, stream>>>(degi);
    k_deg_count<<<(EE + 255) / 256, 256, 0, stream>>>(EI, degi);
    k_prep     <<<32, 256, 0, stream>>>(GW, FW, Wt, FWt);
    k_ln1_gemm <<<(NN + 127) / 128, 256, 0, stream>>>(X, Wt, g1, b1, H);
    k_scan1    <<<NB, 256, 0, stream>>>(degi, rowst, bsum);
    k_scan2    <<<1, 64, 0, stream>>>(bsum);
    k_scan3    <<<NB, 256, 0, stream>>>(rowst, bsum, cursor);
    k_fill     <<<(EE + 255) / 256, 256, 0, stream>>>(EI, cursor, srcs);
    k_gather   <<<(NN + 3) / 4, 256, 0, stream>>>(degi, rowst, srcs, (const unsigned int*)H,
                                                  X, gb, a1, out, mu_arr, rs_arr);
    k_ln2_gemm <<<(NN + 127) / 128, 256, 0, stream>>>(FWt, g2, b2, fb, a2, mu_arr, rs_arr, out);
}

// Round 15
// 442.723 us; speedup vs baseline: 2.3245x; 1.1505x over previous
//
#include <hip/hip_runtime.h>
#include <hip/hip_bf16.h>

#define NN 200000
#define EE 600000
#define DD 128
#define NB 782          // (NN + 255) / 256

typedef __attribute__((ext_vector_type(8))) short short8v;   // 8 bf16 = 4 VGPRs
typedef __attribute__((ext_vector_type(4))) float f32x4;

__device__ __forceinline__ float silu_f(float v) {
    return v * (1.0f / (1.0f + __expf(-v)));
}

__device__ __forceinline__ unsigned int pack_bf2(float a, float b) {
    __hip_bfloat162 hb;
    hb.x = __float2bfloat16(a);
    hb.y = __float2bfloat16(b);
    return *(unsigned int*)&hb;
}

// ---------------- init: degi = 0 ----------------
__global__ void k_init(int* __restrict__ degi) {
    int i = blockIdx.x * 256 + threadIdx.x;
    if (i < NN) degi[i] = 0;
}

// ---------------- degree count (int atomics, excl self-loop) ----------------
__global__ void k_deg_count(const int* __restrict__ ei, int* __restrict__ degi) {
    int e = blockIdx.x * 256 + threadIdx.x;
    if (e < EE) atomicAdd(&degi[ei[EE + e]], 1);  // dst row
}

// ---------------- prep: W,FW (fp32 [k][col]) -> Wt,FWt (bf16 [col][k]) ----------------
__global__ void k_prep(const float* __restrict__ W, const float* __restrict__ FW,
                       unsigned short* __restrict__ Wt, unsigned short* __restrict__ FWt) {
    const int gid = blockIdx.x * 256 + threadIdx.x;  // [0, 8192)
    const int id = gid & 4095;
    const int col = id >> 5;
    const int kb = (id & 31) * 4;
    const float* src = (gid < 4096) ? W : FW;
    unsigned short* dst = (gid < 4096) ? Wt : FWt;
    unsigned short v[4];
#pragma unroll
    for (int i = 0; i < 4; ++i) {
        __hip_bfloat16 h = __float2bfloat16(src[(size_t)(kb + i) * DD + col]);
        v[i] = *(unsigned short*)&h;
    }
    *(uint2*)&dst[col * DD + kb] = *(uint2*)v;
}

// ---------------- scan step 1: per-block exclusive scan + block totals ----------------
__global__ __launch_bounds__(256) void k_scan1(const int* __restrict__ degi,
                                               int* __restrict__ rs, int* __restrict__ bsum) {
    const int tid = threadIdx.x;
    const int i = blockIdx.x * 256 + tid;
    const int lane = tid & 63, wv = tid >> 6;
    int v = (i < NN) ? degi[i] : 0;
    int x = v;
#pragma unroll
    for (int o = 1; o < 64; o <<= 1) { int y = __shfl_up(x, o); if (lane >= o) x += y; }
    __shared__ int wsum[4];
    if (lane == 63) wsum[wv] = x;
    __syncthreads();
    int off = 0;
    for (int w = 0; w < wv; ++w) off += wsum[w];
    const int incl = x + off;
    if (i < NN) rs[i] = incl - v;
    if (tid == 255) bsum[blockIdx.x] = incl;
}

// ---------------- scan step 2: scan the block totals (single wave) ----------------
__global__ void k_scan2(int* __restrict__ bsum) {
    const int lane = threadIdx.x;  // 64 threads
    int carry = 0;
    for (int base = 0; base < NB; base += 64) {
        const int i = base + lane;
        int v = (i < NB) ? bsum[i] : 0;
        int x = v;
#pragma unroll
        for (int o = 1; o < 64; o <<= 1) { int y = __shfl_up(x, o); if (lane >= o) x += y; }
        if (i < NB) bsum[i] = x - v + carry;
        carry += __shfl(x, 63);
    }
}

// ---------------- scan step 3: add block offsets, init cursor ----------------
__global__ void k_scan3(int* __restrict__ rs, const int* __restrict__ bsum,
                        int* __restrict__ cursor) {
    const int i = blockIdx.x * 256 + threadIdx.x;
    if (i < NN) {
        const int v = rs[i] + bsum[blockIdx.x];
        rs[i] = v;
        cursor[i] = v;
    }
}

// ---------------- CSR fill ----------------
__global__ void k_fill(const int* __restrict__ ei, int* __restrict__ cursor,
                       int* __restrict__ srcs) {
    const int e = blockIdx.x * 256 + threadIdx.x;
    if (e < EE) {
        const int s = ei[e], d = ei[EE + e];
        const int pos = atomicAdd(&cursor[d], 1);
        srcs[pos] = s;
    }
}

// ---------------- fused LN1 + bf16 MFMA GEMM: H' = bf16( ((LN(x)*g+b) @ W) * dinv[row] ) ----------------
// 256 thr = 4 waves; block tile 128 rows x 128 cols; wave -> 32-col strip.
// phase A: 4 rows per wave-iteration via 16-lane-group reduce; float4 loads; 16B swizzled LDS store.
__global__ __launch_bounds__(256) void k_ln1_gemm(
    const float* __restrict__ X, const unsigned short* __restrict__ Wt,
    const float* __restrict__ g, const float* __restrict__ b,
    const int* __restrict__ degi,
    unsigned short* __restrict__ H)
{
    __shared__ __align__(16) char As[128 * 256];   // 32 KB swizzled bf16 rows
    __shared__ float dinv_s[128];

    const int tid = threadIdx.x;
    const int w = tid >> 6, lane = tid & 63;
    const int lm = lane & 15, lg = lane >> 4;
    const int sub = lane >> 4;    // row within quad (0..3)
    const int lc = lane & 15;     // col-sixteenth
    const int row0 = blockIdx.x * 128;

    // B fragments (W^T cols for this wave's strip) -> registers, L1-resident
    short8v bfrag[2][4];
#pragma unroll
    for (int ct = 0; ct < 2; ++ct)
#pragma unroll
        for (int ks = 0; ks < 4; ++ks) {
            const int col = w * 32 + ct * 16 + lm;
            bfrag[ct][ks] = *(const short8v*)((const char*)Wt + col * 256 + ks * 64 + lg * 16);
        }

    // phase A: LN stats via 16-lane-group reduce, 4 rows/iteration
    const float4 gv0 = *(const float4*)&g[lc * 8];
    const float4 gv1 = *(const float4*)&g[lc * 8 + 4];
    const float4 bv0 = *(const float4*)&b[lc * 8];
    const float4 bv1 = *(const float4*)&b[lc * 8 + 4];
#pragma unroll
    for (int it = 0; it < 8; ++it) {
        const int r = w * 32 + it * 4 + sub;
        const int grow = row0 + r;
        float4 v0 = make_float4(0.f, 0.f, 0.f, 0.f), v1 = v0;
        if (grow < NN) {
            v0 = *(const float4*)&X[(size_t)grow * DD + lc * 8];
            v1 = *(const float4*)&X[(size_t)grow * DD + lc * 8 + 4];
        }
        float s = v0.x + v0.y + v0.z + v0.w + v1.x + v1.y + v1.z + v1.w;
        float s2 = v0.x * v0.x + v0.y * v0.y + v0.z * v0.z + v0.w * v0.w
                 + v1.x * v1.x + v1.y * v1.y + v1.z * v1.z + v1.w * v1.w;
#pragma unroll
        for (int o = 1; o < 16; o <<= 1) { s += __shfl_xor(s, o); s2 += __shfl_xor(s2, o); }
        const float mu = s * (1.f / DD);
        const float rsv = rsqrtf(s2 * (1.f / DD) - mu * mu + 1e-5f);
        uint4 p;
        p.x = pack_bf2((v0.x - mu) * rsv * gv0.x + bv0.x, (v0.y - mu) * rsv * gv0.y + bv0.y);
        p.y = pack_bf2((v0.z - mu) * rsv * gv0.z + bv0.z, (v0.w - mu) * rsv * gv0.w + bv0.w);
        p.z = pack_bf2((v1.x - mu) * rsv * gv1.x + bv1.x, (v1.y - mu) * rsv * gv1.y + bv1.y);
        p.w = pack_bf2((v1.z - mu) * rsv * gv1.z + bv1.z, (v1.w - mu) * rsv * gv1.w + bv1.w);
        *(uint4*)(As + r * 256 + ((lc * 16) ^ ((r & 7) << 4))) = p;
        if (lc == 0 && grow < NN) dinv_s[r] = rsqrtf(1.0f + (float)degi[grow]);
    }
    __syncthreads();

    // phase B: MFMA
    f32x4 acc[8][2];
#pragma unroll
    for (int rt = 0; rt < 8; ++rt) {
        acc[rt][0] = (f32x4){0.f, 0.f, 0.f, 0.f};
        acc[rt][1] = (f32x4){0.f, 0.f, 0.f, 0.f};
    }
#pragma unroll
    for (int ks = 0; ks < 4; ++ks) {
#pragma unroll
        for (int rt = 0; rt < 8; ++rt) {
            const int row = rt * 16 + lm;
            const short8v a = *(const short8v*)(As + row * 256 + ((ks * 64 + lg * 16) ^ ((row & 7) << 4)));
            acc[rt][0] = __builtin_amdgcn_mfma_f32_16x16x32_bf16(a, bfrag[0][ks], acc[rt][0], 0, 0, 0);
            acc[rt][1] = __builtin_amdgcn_mfma_f32_16x16x32_bf16(a, bfrag[1][ks], acc[rt][1], 0, 0, 0);
        }
    }

    // epilogue: H' = bf16(h * dinv[row])  (C/D layout: col = lane&15, row = (lane>>4)*4 + i)
#pragma unroll
    for (int rt = 0; rt < 8; ++rt)
#pragma unroll
        for (int ct = 0; ct < 2; ++ct)
#pragma unroll
            for (int i = 0; i < 4; ++i) {
                const int lr = rt * 16 + lg * 4 + i;
                const int grow = row0 + lr;
                if (grow < NN) {
                    const int col = w * 32 + ct * 16 + lm;
                    __hip_bfloat16 hv = __float2bfloat16(acc[rt][ct][i] * dinv_s[lr]);
                    H[(size_t)grow * DD + col] = *(unsigned short*)&hv;
                }
            }
}

// ---------------- gather: per-node wave; acc = sum H'[srcs] + H'[self]; x1 = x + a1*silu(dinv*acc + gb) ----------------
__global__ __launch_bounds__(256) void k_gather(
    const int* __restrict__ degi, const int* __restrict__ rs, const int* __restrict__ srcs,
    const unsigned int* __restrict__ Hu,       // H' as bf16x2 dwords (pre-scaled by dinv[src])
    const float* __restrict__ X, const float* __restrict__ gcnb,
    const float* __restrict__ a1p,
    float* __restrict__ out,                   // x1
    float* __restrict__ mu_arr, float* __restrict__ rs_arr)
{
    const int node = blockIdx.x * 4 + (threadIdx.x >> 6);
    const int lane = threadIdx.x & 63;
    if (node >= NN) return;

    const int dcount = degi[node];
    const float dinv_d = rsqrtf(1.0f + (float)dcount);

    // self-loop: H'[node] (already includes dinv[node])
    const unsigned int u = Hu[(size_t)node * 64 + lane];
    float ax = __uint_as_float(u << 16);
    float ay = __uint_as_float(u & 0xffff0000u);
    float bx = 0.f, by = 0.f;

    int base = rs[node];
    int remaining = dcount;
    while (remaining > 0) {
        const int cnt = remaining < 64 ? remaining : 64;
        int sp = 0;
        if (lane < cnt) sp = srcs[base + lane];
        int t = 0;
        for (; t + 1 < cnt; t += 2) {
            const int s0 = __shfl(sp, t);
            const int s1 = __shfl(sp, t + 1);
            const unsigned int u0 = Hu[(size_t)s0 * 64 + lane];
            const unsigned int u1 = Hu[(size_t)s1 * 64 + lane];
            ax += __uint_as_float(u0 << 16);
            ay += __uint_as_float(u0 & 0xffff0000u);
            bx += __uint_as_float(u1 << 16);
            by += __uint_as_float(u1 & 0xffff0000u);
        }
        if (t < cnt) {
            const int s0 = __shfl(sp, t);
            const unsigned int u0 = Hu[(size_t)s0 * 64 + lane];
            ax += __uint_as_float(u0 << 16);
            ay += __uint_as_float(u0 & 0xffff0000u);
        }
        remaining -= cnt;
        base += cnt;
    }
    const float mx = (ax + bx) * dinv_d;
    const float my = (ay + by) * dinv_d;

    const float a1 = *a1p;
    const float2 gb = ((const float2*)gcnb)[lane];
    const float2 xv = ((const float2*)X)[(size_t)node * 64 + lane];
    float2 o;
    o.x = xv.x + a1 * silu_f(mx + gb.x);
    o.y = xv.y + a1 * silu_f(my + gb.y);
    ((float2*)out)[(size_t)node * 64 + lane] = o;

    // LN2 stats for this row
    float s = o.x + o.y;
    float s2 = o.x * o.x + o.y * o.y;
    for (int of = 32; of; of >>= 1) { s += __shfl_xor(s, of); s2 += __shfl_xor(s2, of); }
    if (lane == 0) {
        const float mu = s * (1.f / DD);
        const float var = s2 * (1.f / DD) - mu * mu;
        mu_arr[node] = mu;
        rs_arr[node] = rsqrtf(var + 1e-5f);
    }
}

// ---------------- fused LN2 + bf16 MFMA GEMM + epilogue: out = x1 + a2*silu(f + fb) ----------------
__global__ __launch_bounds__(256) void k_ln2_gemm(
    const unsigned short* __restrict__ FWt,
    const float* __restrict__ g2, const float* __restrict__ b2,
    const float* __restrict__ fb, const float* __restrict__ a2p,
    const float* __restrict__ mu_arr, const float* __restrict__ rs_arr,
    float* __restrict__ out)   // x1 on entry, final output on exit
{
    __shared__ __align__(16) char As[128 * 256];

    const int tid = threadIdx.x;
    const int w = tid >> 6, lane = tid & 63;
    const int lm = lane & 15, lg = lane >> 4;
    const int sub = lane >> 4;
    const int lc = lane & 15;
    const int row0 = blockIdx.x * 128;

    short8v bfrag[2][4];
#pragma unroll
    for (int ct = 0; ct < 2; ++ct)
#pragma unroll
        for (int ks = 0; ks < 4; ++ks) {
            const int col = w * 32 + ct * 16 + lm;
            bfrag[ct][ks] = *(const short8v*)((const char*)FWt + col * 256 + ks * 64 + lg * 16);
        }
    const float fbv0 = fb[w * 32 + lm];
    const float fbv1 = fb[w * 32 + 16 + lm];

    // phase A: normalize x1 with precomputed stats, 4 rows/iteration, float4 loads
    const float4 gv0 = *(const float4*)&g2[lc * 8];
    const float4 gv1 = *(const float4*)&g2[lc * 8 + 4];
    const float4 bv0 = *(const float4*)&b2[lc * 8];
    const float4 bv1 = *(const float4*)&b2[lc * 8 + 4];
#pragma unroll
    for (int it = 0; it < 8; ++it) {
        const int r = w * 32 + it * 4 + sub;
        const int grow = row0 + r;
        float4 v0 = make_float4(0.f, 0.f, 0.f, 0.f), v1 = v0;
        float mu = 0.f, rsv = 0.f;
        if (grow < NN) {
            v0 = *(const float4*)&out[(size_t)grow * DD + lc * 8];
            v1 = *(const float4*)&out[(size_t)grow * DD + lc * 8 + 4];
            mu = mu_arr[grow];
            rsv = rs_arr[grow];
        }
        uint4 p;
        p.x = pack_bf2((v0.x - mu) * rsv * gv0.x + bv0.x, (v0.y - mu) * rsv * gv0.y + bv0.y);
        p.y = pack_bf2((v0.z - mu) * rsv * gv0.z + bv0.z, (v0.w - mu) * rsv * gv0.w + bv0.w);
        p.z = pack_bf2((v1.x - mu) * rsv * gv1.x + bv1.x, (v1.y - mu) * rsv * gv1.y + bv1.y);
        p.w = pack_bf2((v1.z - mu) * rsv * gv1.z + bv1.z, (v1.w - mu) * rsv * gv1.w + bv1.w);
        *(uint4*)(As + r * 256 + ((lc * 16) ^ ((r & 7) << 4))) = p;
    }
    __syncthreads();

    f32x4 acc[8][2];
#pragma unroll
    for (int rt = 0; rt < 8; ++rt) {
        acc[rt][0] = (f32x4){0.f, 0.f, 0.f, 0.f};
        acc[rt][1] = (f32x4){0.f, 0.f, 0.f, 0.f};
    }
#pragma unroll
    for (int ks = 0; ks < 4; ++ks) {
#pragma unroll
        for (int rt = 0; rt < 8; ++rt) {
            const int row = rt * 16 + lm;
            const short8v a = *(const short8v*)(As + row * 256 + ((ks * 64 + lg * 16) ^ ((row & 7) << 4)));
            acc[rt][0] = __builtin_amdgcn_mfma_f32_16x16x32_bf16(a, bfrag[0][ks], acc[rt][0], 0, 0, 0);
            acc[rt][1] = __builtin_amdgcn_mfma_f32_16x16x32_bf16(a, bfrag[1][ks], acc[rt][1], 0, 0, 0);
        }
    }

    const float a2 = *a2p;
#pragma unroll
    for (int rt = 0; rt < 8; ++rt)
#pragma unroll
        for (int ct = 0; ct < 2; ++ct)
#pragma unroll
            for (int i = 0; i < 4; ++i) {
                const int grow = row0 + rt * 16 + lg * 4 + i;
                if (grow < NN) {
                    const int col = w * 32 + ct * 16 + lm;
                    const float fbc = ct ? fbv1 : fbv0;
                    const size_t idx = (size_t)grow * DD + col;
                    out[idx] = out[idx] + a2 * silu_f(acc[rt][ct][i] + fbc);
                }
            }
}

extern "C" void kernel_launch(void* const* d_in, const int* in_sizes, int n_in,
                              void* d_out, int out_size, void* d_ws, size_t ws_size,
                              hipStream_t stream)
{
    const float* X  = (const float*)d_in[0];
    const int*   EI = (const int*)d_in[1];
    const float* g1 = (const float*)d_in[2];
    const float* b1 = (const float*)d_in[3];
    const float* GW = (const float*)d_in[4];
    const float* gb = (const float*)d_in[5];
    const float* a1 = (const float*)d_in[6];
    const float* a2 = (const float*)d_in[7];
    const float* g2 = (const float*)d_in[8];
    const float* b2 = (const float*)d_in[9];
    const float* FW = (const float*)d_in[10];
    const float* fb = (const float*)d_in[11];
    float* out = (float*)d_out;

    char* ws = (char*)d_ws;
    int*            degi    = (int*)ws;                        //    800,000 B
    unsigned short* H       = (unsigned short*)(ws + 800000);  // 51,200,000 B
    int*            rowst   = (int*)(ws + 52000000);           //    800,000 B
    int*            cursor  = (int*)(ws + 52800000);           //    800,000 B
    int*            srcs    = (int*)(ws + 53600000);           //  2,400,000 B
    int*            bsum    = (int*)(ws + 56000000);           //      3,200 B
    float*          mu_arr  = (float*)(ws + 56016000);         //    800,000 B
    float*          rs_arr  = (float*)(ws + 56816000);         //    800,000 B
    unsigned short* Wt      = (unsigned short*)(ws + 57616000);//     32,768 B
    unsigned short* FWt     = (unsigned short*)(ws + 57648768);//     32,768 B
    // total ws use: 57,681,536 B

    k_init     <<<NB, 256, 0, stream>>>(degi);
    k_deg_count<<<(EE + 255) / 256, 256, 0, stream>>>(EI, degi);
    k_prep     <<<32, 256, 0, stream>>>(GW, FW, Wt, FWt);
    k_ln1_gemm <<<(NN + 127) / 128, 256, 0, stream>>>(X, Wt, g1, b1, degi, H);
    k_scan1    <<<NB, 256, 0, stream>>>(degi, rowst, bsum);
    k_scan2    <<<1, 64, 0, stream>>>(bsum);
    k_scan3    <<<NB, 256, 0, stream>>>(rowst, bsum, cursor);
    k_fill     <<<(EE + 255) / 256, 256, 0, stream>>>(EI, cursor, srcs);
    k_gather   <<<(NN + 3) / 4, 256, 0, stream>>>(degi, rowst, srcs, (const unsigned int*)H,
                                                  X, gb, a1, out, mu_arr, rs_arr);
    k_ln2_gemm <<<(NN + 127) / 128, 256, 0, stream>>>(FWt, g2, b2, fb, a2, mu_arr, rs_arr, out);
}